// Round 12
// baseline (392.332 us; speedup 1.0000x reference)
//
#include <hip/hip_runtime.h>

// Chamfer NN squared distances via MFMA (f16 hi/lo emulation).
// Round-12: DIAGNOSTIC round. Real kernel = R11 unchanged (MODE 0, REPS 1,
// -> d_out). Four repeat-amplified diagnostic clones -> d_ws, each >44us so
// they appear in rocprof top-5 (the 268MB ws-poison fills at ~40us have hidden
// every kernel since R8):
//   MODE 0 REPS 4: baseline counters for the R11 structure
//   MODE 1 REPS 6: no-min   (1 min3 per MFMA pair; d[0] use keeps MFMA alive)
//   MODE 2 REPS 6: no-ds-read (bf read once/chunk; loop-carried mfma acc,
//                              DCE-proof); isolates ds_read share
//   MODE 3 REPS 4: 2-A-frag candidate (1 ds_read -> 2 MFMA, 64 rows/wave,
//                              ref-dim split across blockIdx.x parity)
//
// Math (all modes): d(q,r) = |q|^2+|r|^2-2q.r in ONE mfma_f32_32x32x16_f16,
// 13 K-slots (layout in packA/packB). Error ~1e-4 vs 0.12 threshold.

typedef _Float16 v8h  __attribute__((ext_vector_type(8)));
typedef float    v16f __attribute__((ext_vector_type(16)));

constexpr int TPB   = 256;        // 4 waves
constexpr int RPW   = 32;         // rows per wave (1 A-fragment), modes 0-2
constexpr int RPB   = 4 * RPW;    // 128 rows per block, modes 0-2
constexpr int CHUNK = 512;        // refs per buffer (2 halves x 8 KB)

__device__ __forceinline__ void split3(float x, float y, float z,
    _Float16& hx, _Float16& hy, _Float16& hz,
    _Float16& lx, _Float16& ly, _Float16& lz,
    _Float16& sh, _Float16& sl)
{
    const float s = fmaf(z, z, fmaf(y, y, x * x));
    hx = (_Float16)x; hy = (_Float16)y; hz = (_Float16)z;
    lx = (_Float16)(x - (float)hx);
    ly = (_Float16)(y - (float)hy);
    lz = (_Float16)(z - (float)hz);
    sh = (_Float16)s;
    sl = (_Float16)(s - (float)sh);
}

__device__ __forceinline__ v8h packA(const float* __restrict__ qb, int row, int g)
{
    const float x = qb[(size_t)row * 3 + 0];
    const float y = qb[(size_t)row * 3 + 1];
    const float z = qb[(size_t)row * 3 + 2];
    _Float16 hx, hy, hz, lx, ly, lz, sh, sl;
    split3(x, y, z, hx, hy, hz, lx, ly, lz, sh, sl);
    const _Float16 nhx = (_Float16)(-2.f * x);
    const _Float16 nhy = (_Float16)(-2.f * y);
    const _Float16 nhz = (_Float16)(-2.f * z);
    const _Float16 nlx = (_Float16)(-2.f * (float)lx);
    const _Float16 nly = (_Float16)(-2.f * (float)ly);
    const _Float16 nlz = (_Float16)(-2.f * (float)lz);
    const _Float16 one = (_Float16)1.f, zz = (_Float16)0.f;
    const v8h A0 = {nhx, nhy, nhz, nhx, nhy, nhz, nlx, nly};
    const v8h A1 = {nlz, one, one, sh, sl, zz, zz, zz};
    return g ? A1 : A0;
}

__device__ __forceinline__ void packB(float x, float y, float z, uint4& h0, uint4& h1)
{
    _Float16 hx, hy, hz, lx, ly, lz, sh, sl;
    split3(x, y, z, hx, hy, hz, lx, ly, lz, sh, sl);
    const _Float16 one = (_Float16)1.f, zz = (_Float16)0.f;
    const v8h B0 = {hx, hy, hz, lx, ly, lz, hx, hy};
    const v8h B1 = {hz, sh, sl, one, one, zz, zz, zz};
    h0 = __builtin_bit_cast(uint4, B0);
    h1 = __builtin_bit_cast(uint4, B1);
}

template<int MODE, int REPS>
__global__ __launch_bounds__(TPB)
__attribute__((amdgpu_waves_per_eu(4, 4)))
void nnd_k(const float* __restrict__ p1, const float* __restrict__ p2,
           float* __restrict__ out, int B, int N, int M)
{
    const int dir = blockIdx.z;          // 0: q=p1,r=p2 (dist1); 1: swapped
    const int b   = blockIdx.y;
    const float* __restrict__ q = dir ? p2 : p1;
    const float* __restrict__ r = dir ? p1 : p2;
    const int Nq = dir ? M : N;
    const int Nr = dir ? N : M;
    float* __restrict__ o = out + (dir ? (size_t)B * N : 0) + (size_t)b * Nq;

    const int tid  = threadIdx.x;
    const int w    = tid >> 6;
    const int lane = tid & 63;
    const int c    = lane & 31;          // MFMA row (A) / col (B) within tile
    const int g    = lane >> 5;          // k-half

    int row0, r0, nrefs;
    if constexpr (MODE == 3) {
        row0  = (blockIdx.x >> 1) * 256 + w * 64;   // 2 A-frags: rows row0, row0+32
        r0    = (blockIdx.x & 1) * (Nr / 2);        // ref-dim split by x parity
        nrefs = Nr / 2;
    } else {
        row0  = blockIdx.x * RPB + w * RPW;
        r0    = 0;
        nrefs = Nr;
    }

    const float* qb = q + (size_t)b * Nq * 3;
    const v8h a0 = packA(qb, row0 + c, g);
    v8h a1 = a0;
    if constexpr (MODE == 3) a1 = packA(qb, row0 + 32 + c, g);

    v16f zc;
#pragma unroll
    for (int i = 0; i < 16; ++i) zc[i] = 0.f;
    v16f acA = zc, acB = zc;             // MODE 2 loop-carried accumulators
    float rm[16], rm1[16];
#pragma unroll
    for (int i = 0; i < 16; ++i) { rm[i] = 3.0e38f; rm1[i] = 3.0e38f; }

    __shared__ uint4 sb[2][2 * CHUNK];   // [buf][half*CHUNK + slot]
    const float* rb = r + (size_t)b * Nr * 3;
    const int NT = nrefs / CHUNK;        // 8 (modes 0-2) / 4 (mode 3): EVEN ->
                                         // rep-boundary buf0 write is race-free

    for (int rep = 0; rep < REPS; ++rep) {
        // ---- prologue: stage first chunk into buf 0 ----
        {
            const float2* s2 = (const float2*)(rb + (size_t)r0 * 3);
            const float2 A  = s2[3 * tid + 0];
            const float2 C2 = s2[3 * tid + 1];
            const float2 E  = s2[3 * tid + 2];
            uint4 h00, h01, h10, h11;
            packB(A.x, A.y, C2.x, h00, h01);
            packB(C2.y, E.x, E.y, h10, h11);
            sb[0][tid]               = h00;
            sb[0][TPB + tid]         = h10;
            sb[0][CHUNK + tid]       = h01;
            sb[0][CHUNK + TPB + tid] = h11;
        }
        __syncthreads();

        int cur = 0;
        for (int t = 0; t < NT; ++t) {
            const bool more = (t + 1 < NT);
            // (1) issue global loads for next chunk (fly under compute)
            float2 A, C2, E;
            if (more) {
                const float2* s2 = (const float2*)(rb + (size_t)(r0 + (t + 1) * CHUNK) * 3);
                A  = s2[3 * tid + 0];
                C2 = s2[3 * tid + 1];
                E  = s2[3 * tid + 2];
            }
            // (2) compute on buf[cur]
            const uint4* sbase = &sb[cur][g * CHUNK];
            if constexpr (MODE == 0 || MODE == 1) {
#pragma unroll 2
                for (int st = 0; st < CHUNK / 32; st += 2) {
                    const v8h bfA = __builtin_bit_cast(v8h, sbase[st * 32 + c]);
                    const v8h bfB = __builtin_bit_cast(v8h, sbase[st * 32 + 32 + c]);
                    const v16f da = __builtin_amdgcn_mfma_f32_32x32x16_f16(a0, bfA, zc, 0, 0, 0);
                    const v16f db = __builtin_amdgcn_mfma_f32_32x32x16_f16(a0, bfB, zc, 0, 0, 0);
                    if constexpr (MODE == 0) {
#pragma unroll
                        for (int i = 0; i < 16; ++i)
                            rm[i] = fminf(fminf(da[i], db[i]), rm[i]);   // v_min3
                    } else {
                        // no-min diag: 1 min3 keeps both MFMAs live, drops 15/16 VALU
                        rm[0] = fminf(fminf(da[0], db[0]), rm[0]);
                    }
                }
            } else if constexpr (MODE == 2) {
                // no-ds-read diag: bf read ONCE per chunk; loop-carried mfma acc
                const v8h bfA = __builtin_bit_cast(v8h, sbase[c]);
                const v8h bfB = __builtin_bit_cast(v8h, sbase[32 + c]);
#pragma unroll 2
                for (int st = 0; st < CHUNK / 32; st += 2) {
                    acA = __builtin_amdgcn_mfma_f32_32x32x16_f16(a0, bfA, acA, 0, 0, 0);
                    acB = __builtin_amdgcn_mfma_f32_32x32x16_f16(a0, bfB, acB, 0, 0, 0);
#pragma unroll
                    for (int i = 0; i < 16; ++i)
                        rm[i] = fminf(fminf(acA[i], acB[i]), rm[i]);
                }
            } else {  // MODE 3: 2 A-frags share each bf read
#pragma unroll 2
                for (int st = 0; st < CHUNK / 32; ++st) {
                    const v8h bf = __builtin_bit_cast(v8h, sbase[st * 32 + c]);
                    const v16f d0 = __builtin_amdgcn_mfma_f32_32x32x16_f16(a0, bf, zc, 0, 0, 0);
                    const v16f d1 = __builtin_amdgcn_mfma_f32_32x32x16_f16(a1, bf, zc, 0, 0, 0);
#pragma unroll
                    for (int i = 0; i < 16; ++i) rm[i]  = fminf(rm[i],  d0[i]);
#pragma unroll
                    for (int i = 0; i < 16; ++i) rm1[i] = fminf(rm1[i], d1[i]);
                }
            }
            // (3) pack + write next chunk into buf[cur^1]
            if (more) {
                uint4 h00, h01, h10, h11;
                packB(A.x, A.y, C2.x, h00, h01);
                packB(C2.y, E.x, E.y, h10, h11);
                uint4* d = sb[cur ^ 1];
                d[tid]               = h00;
                d[TPB + tid]         = h10;
                d[CHUNK + tid]       = h01;
                d[CHUNK + TPB + tid] = h11;
                __syncthreads();
            }
            cur ^= 1;
        }
    }

    // ---- epilogue: min over 32 columns (bits 0-4), direct store ----
#pragma unroll
    for (int i = 0; i < 16; ++i) {
        float v = rm[i];
        v = fminf(v, __shfl_xor(v, 1));
        v = fminf(v, __shfl_xor(v, 2));
        v = fminf(v, __shfl_xor(v, 4));
        v = fminf(v, __shfl_xor(v, 8));
        v = fminf(v, __shfl_xor(v, 16));
        rm[i] = v;
    }
    if constexpr (MODE == 3) {
#pragma unroll
        for (int i = 0; i < 16; ++i) {
            float v = rm1[i];
            v = fminf(v, __shfl_xor(v, 1));
            v = fminf(v, __shfl_xor(v, 2));
            v = fminf(v, __shfl_xor(v, 4));
            v = fminf(v, __shfl_xor(v, 8));
            v = fminf(v, __shfl_xor(v, 16));
            rm1[i] = v;
        }
    }
    if (c == 0) {
#pragma unroll
        for (int i = 0; i < 16; ++i) {
            const int rr = (i & 3) + 8 * (i >> 2) + 4 * g;  // verified C layout
            o[row0 + rr] = rm[i];
            if constexpr (MODE == 3) o[row0 + 32 + rr] = rm1[i];
        }
    }
}

// ---------------- fallback: round-3 identity-folded VALU kernel ----------------
constexpr int FTPB   = 256;
constexpr int FIPT   = 4;
constexpr int FTILE  = 512;
constexpr int FSPLIT = 8;

__global__ __launch_bounds__(FTPB, 4) void nnd_fold(
    const float* __restrict__ p1, const float* __restrict__ p2,
    float* __restrict__ out, int B, int N, int M)
{
    const int z   = blockIdx.z;
    const int dir = z / FSPLIT;
    const int s   = z % FSPLIT;
    const int b   = blockIdx.y;

    const float* __restrict__ q = dir ? p2 : p1;
    const float* __restrict__ r = dir ? p1 : p2;
    const int Nq = dir ? M : N;
    const int Nr = dir ? N : M;
    float* __restrict__ o = out + (dir ? (size_t)B * N : 0) + (size_t)b * Nq;

    const int tid = threadIdx.x;
    const float* qb = q + (size_t)b * Nq * 3;
    float qx[FIPT], qy[FIPT], qz[FIPT], qs[FIPT], mn[FIPT];
    int   qi[FIPT];
#pragma unroll
    for (int i = 0; i < FIPT; ++i) {
        qi[i] = blockIdx.x * (FTPB * FIPT) + i * FTPB + tid;
        if (qi[i] < Nq) {
            qx[i] = qb[qi[i] * 3 + 0]; qy[i] = qb[qi[i] * 3 + 1]; qz[i] = qb[qi[i] * 3 + 2];
        } else { qx[i] = qy[i] = qz[i] = 0.f; }
        float sq = qx[i] * qx[i];
        sq = fmaf(qy[i], qy[i], sq); sq = fmaf(qz[i], qz[i], sq);
        qs[i] = sq; mn[i] = 3.0e38f;
    }
    const int per = (Nr + FSPLIT - 1) / FSPLIT;
    const int r0 = s * per, r1 = min(Nr, r0 + per);
    __shared__ float4 shm[FTILE];
    const float* rb = r + (size_t)b * Nr * 3;
    for (int ts = r0; ts < r1; ts += FTILE) {
        const int npts = min(FTILE, r1 - ts);
        __syncthreads();
        if (npts == FTILE && ((((size_t)b * Nr + (size_t)ts) * 3) & 1) == 0) {
            const float2* src = (const float2*)(rb + (size_t)ts * 3);
            float2 a = src[3 * tid + 0], c2 = src[3 * tid + 1], e = src[3 * tid + 2];
            float s0 = a.x * a.x; s0 = fmaf(a.y, a.y, s0); s0 = fmaf(c2.x, c2.x, s0);
            float s1 = c2.y * c2.y; s1 = fmaf(e.x, e.x, s1); s1 = fmaf(e.y, e.y, s1);
            shm[2 * tid + 0] = make_float4(-2.f * a.x, -2.f * a.y, -2.f * c2.x, s0);
            shm[2 * tid + 1] = make_float4(-2.f * c2.y, -2.f * e.x, -2.f * e.y, s1);
        } else {
#pragma unroll
            for (int k = 0; k < 2; ++k) {
                const int pl = 2 * tid + k;
                float4 v = make_float4(0.f, 0.f, 0.f, 3.0e38f);
                if (pl < npts) {
                    const float* pp = rb + (size_t)(ts + pl) * 3;
                    float sq = pp[0] * pp[0];
                    sq = fmaf(pp[1], pp[1], sq); sq = fmaf(pp[2], pp[2], sq);
                    v = make_float4(-2.f * pp[0], -2.f * pp[1], -2.f * pp[2], sq);
                }
                shm[pl] = v;
            }
        }
        __syncthreads();
#pragma unroll 8
        for (int j = 0; j < FTILE; ++j) {
            const float4 p = shm[j];
#pragma unroll
            for (int i = 0; i < FIPT; ++i) {
                float t = fmaf(p.x, qx[i], p.w);
                t = fmaf(p.y, qy[i], t);
                t = fmaf(p.z, qz[i], t);
                mn[i] = fminf(mn[i], t);
            }
        }
    }
#pragma unroll
    for (int i = 0; i < FIPT; ++i)
        if (qi[i] < Nq) atomicMin((int*)&o[qi[i]], __float_as_int(mn[i] + qs[i]));
}

extern "C" void kernel_launch(void* const* d_in, const int* in_sizes, int n_in,
                              void* d_out, int out_size, void* d_ws, size_t ws_size,
                              hipStream_t stream) {
    const float* p1 = (const float*)d_in[0];
    const float* p2 = (const float*)d_in[1];
    float* out = (float*)d_out;

    const int B = 16;
    const int N = in_sizes[0] / (B * 3);
    const int M = in_sizes[1] / (B * 3);

    const bool mfma_ok = (N == M) && (N % 256 == 0) && (N % CHUNK == 0);

    if (mfma_ok) {
        dim3 grid(N / RPB, B, 2);   // (32, 16, 2)
        // real kernel: unchanged R11 structure, direct stores cover all outputs
        nnd_k<0, 1><<<grid, TPB, 0, stream>>>(p1, p2, out, B, N, M);
        // diagnostics -> d_ws (repeat-amplified to beat the 40us poison fills
        // into the rocprof top-5; outputs are scratch garbage by design)
        if (ws_size >= (size_t)out_size * sizeof(float)) {
            float* dg = (float*)d_ws;
            nnd_k<0, 4><<<grid, TPB, 0, stream>>>(p1, p2, dg, B, N, M);
            nnd_k<1, 6><<<grid, TPB, 0, stream>>>(p1, p2, dg, B, N, M);
            nnd_k<2, 6><<<grid, TPB, 0, stream>>>(p1, p2, dg, B, N, M);
            nnd_k<3, 4><<<grid, TPB, 0, stream>>>(p1, p2, dg, B, N, M);
        }
    } else {
        hipMemsetAsync(d_out, 0x7f, (size_t)out_size * sizeof(float), stream);
        const int qmax = (N > M) ? N : M;
        dim3 grid((qmax + FTPB * FIPT - 1) / (FTPB * FIPT), B, 2 * FSPLIT);
        nnd_fold<<<grid, FTPB, 0, stream>>>(p1, p2, out, B, N, M);
    }
}